// Round 6
// baseline (4451.640 us; speedup 1.0000x reference)
//
#include <hip/hip_runtime.h>
#include <cstdint>
#include <cstddef>
#include <cstring>

#define LSEQ 512
#define BATCH 64
#define DIM 256
#define HID 256
#define NTAG 11

typedef float vf4 __attribute__((ext_vector_type(4)));
typedef __bf16 bf16x8 __attribute__((ext_vector_type(8)));
typedef float f32x4 __attribute__((ext_vector_type(4)));
typedef _Float16 h2 __attribute__((ext_vector_type(2)));
typedef unsigned short u16;

static __device__ __forceinline__ float dot2_f16(unsigned int w, unsigned int h, float acc)
{
#if __has_builtin(__builtin_amdgcn_fdot2)
    return __builtin_amdgcn_fdot2(__builtin_bit_cast(h2, w),
                                  __builtin_bit_cast(h2, h), acc, false);
#else
    h2 a = __builtin_bit_cast(h2, w), b = __builtin_bit_cast(h2, h);
    acc = fmaf((float)a.x, (float)b.x, acc);
    return fmaf((float)a.y, (float)b.y, acc);
#endif
}

// ---------------- fp32 -> bf16 (RNE) convert ----------------
__global__ void __launch_bounds__(256) cvt_bf16(
    const float* __restrict__ src, u16* __restrict__ dst, int n4)
{
    int i = blockIdx.x * blockDim.x + threadIdx.x;
    const int stride = gridDim.x * blockDim.x;
    for (; i < n4; i += stride) {
        float4 f = ((const float4*)src)[i];
        ushort4 r;
        unsigned int u;
        u = __float_as_uint(f.x); u += 0x7FFFu + ((u >> 16) & 1u); r.x = (u16)(u >> 16);
        u = __float_as_uint(f.y); u += 0x7FFFu + ((u >> 16) & 1u); r.y = (u16)(u >> 16);
        u = __float_as_uint(f.z); u += 0x7FFFu + ((u >> 16) & 1u); r.z = (u16)(u >> 16);
        u = __float_as_uint(f.w); u += 0x7FFFu + ((u >> 16) & 1u); r.w = (u16)(u >> 16);
        ((ushort4*)dst)[i] = r;
    }
}

// ---------------- fp32 -> fp16 (RNE) convert ----------------
__global__ void __launch_bounds__(256) cvt_f16(
    const float* __restrict__ src, u16* __restrict__ dst, int n4)
{
    int i = blockIdx.x * blockDim.x + threadIdx.x;
    const int stride = gridDim.x * blockDim.x;
    for (; i < n4; i += stride) {
        float4 f = ((const float4*)src)[i];
        ushort4 r;
        r.x = __builtin_bit_cast(u16, (_Float16)f.x);
        r.y = __builtin_bit_cast(u16, (_Float16)f.y);
        r.z = __builtin_bit_cast(u16, (_Float16)f.z);
        r.w = __builtin_bit_cast(u16, (_Float16)f.w);
        ((ushort4*)dst)[i] = r;
    }
}

// ---------------- input GEMM via bf16 MFMA (+gather, +bias) ----------------
__global__ void __launch_bounds__(256) gemm_in(
    const int* __restrict__ sent, const u16* __restrict__ embb,
    const u16* __restrict__ w16f, const u16* __restrict__ w16b,
    const float* __restrict__ bf_, const float* __restrict__ bb_,
    float* __restrict__ Gin, int t0, int CT)
{
    const int mtile = blockIdx.x, ntile = blockIdx.y, dir = blockIdx.z;
    const u16* __restrict__ W16 = dir ? w16b : w16f;
    const float* __restrict__ bias = dir ? bb_ : bf_;
    const int tid = threadIdx.x;
    const int wave = tid >> 6, lane = tid & 63;
    const int wm = wave & 1, wn = wave >> 1;

    __shared__ u16 Asm[128][40];   // [m][k] pitch 40 (2-way max on frag reads)
    __shared__ u16 Bsm[128][40];   // [n][k]

    const int row = tid >> 1, half = tid & 1;
    const u16* ap;
    {
        int m_g = mtile * 128 + row;
        int tl = m_g >> 6, b = m_g & 63;
        int tg = t0 + tl;
        int tt = dir ? (LSEQ - 1 - tg) : tg;
        ap = embb + (size_t)sent[b * LSEQ + tt] * DIM;
    }
    const u16* bp = W16 + (size_t)(ntile * 128 + row) * DIM;

    f32x4 acc[4][4];
#pragma unroll
    for (int i = 0; i < 4; i++)
#pragma unroll
        for (int j = 0; j < 4; j++) acc[i][j] = (f32x4){0.f, 0.f, 0.f, 0.f};

    const int col = lane & 15, quad = lane >> 4;

    for (int ki = 0; ki < 8; ki++) {
        const int k0 = ki * 32;
        __syncthreads();
        {
            uint4 a0 = *(const uint4*)(ap + k0 + half * 16);
            uint4 a1 = *(const uint4*)(ap + k0 + half * 16 + 8);
            uint4 b0 = *(const uint4*)(bp + k0 + half * 16);
            uint4 b1 = *(const uint4*)(bp + k0 + half * 16 + 8);
            *(uint4*)&Asm[row][half * 16 + 0] = a0;
            *(uint4*)&Asm[row][half * 16 + 8] = a1;
            *(uint4*)&Bsm[row][half * 16 + 0] = b0;
            *(uint4*)&Bsm[row][half * 16 + 8] = b1;
        }
        __syncthreads();

        bf16x8 af[4], bg[4];
#pragma unroll
        for (int i = 0; i < 4; i++) {
            af[i] = *(const bf16x8*)&Asm[wm * 64 + i * 16 + col][quad * 8];
            bg[i] = *(const bf16x8*)&Bsm[wn * 64 + i * 16 + col][quad * 8];
        }
#pragma unroll
        for (int mt = 0; mt < 4; mt++)
#pragma unroll
            for (int nt = 0; nt < 4; nt++)
                acc[mt][nt] = __builtin_amdgcn_mfma_f32_16x16x32_bf16(
                    af[mt], bg[nt], acc[mt][nt], 0, 0, 0);
    }

#pragma unroll
    for (int nt = 0; nt < 4; nt++) {
        const int n_g = ntile * 128 + wn * 64 + nt * 16 + col;
        const float bv = bias[n_g];
        const int q = n_g >> 8, e = n_g & 255;
#pragma unroll
        for (int mt = 0; mt < 4; mt++)
#pragma unroll
            for (int r = 0; r < 4; r++) {
                const int m_g = mtile * 128 + wm * 64 + mt * 16 + quad * 4 + r;
                const int tl = m_g >> 6, b = m_g & 63;
                Gin[(((size_t)(dir * CT + tl) * 64 + b) * 256 + e) * 4 + q]
                    = acc[mt][nt][r] + bv;
            }
    }
}

// ---------------- persistent bidirectional LSTM recurrence ------
// r5 post-mortem: CT=256 (ws=268MB) => lstm_rec runs TWICE; 845us/dispatch
// = 7920 cyc/step; lstm = 80% of total.  The serial per-step chain =
// compute (~2400: DS 24 b128 + 32 shfl; VALU ~2100) + publish->MALL->poll
// (~1500-2000) + residual.  This round halves the per-member compute on
// that chain:
//   512 WGs = 32 groups x 16 MEMBERS (member w owns 16 ees), 2 WGs/CU
//   (independent chains interleave on a CU; LDS 40KB/WG so both fit).
// Per thread (ep = tid>>4 -> ee = 16w+ep; ks = tid&15 -> k-halves
// [16ks,+16)): 4 gate rows x 4 batches, 128 dot2, 8 weight b128 (private
// 33-dword pitch block, conflict-free: bank = (tid+4s) mod 32) + 8 h b128
// (pitch-12-per-ks swizzle: dword d -> 12*(d>>3)+(d&7); banks 12g mod 32
// = 2-way only, FREE; fixes r4/r5's 4-way h aliasing).
// Reduce-scatter (20 shfl): xor1/xor2 scatter the batch bits (b = ks&3),
// xor4/xor8 allreduce => every lane holds all 4 gates of (ee, bbase+(ks&3))
// (4x replicated); ks<4 publishes.  TAG-IN-DATA exchange unchanged.
__global__ void __launch_bounds__(256, 2) lstm_rec(
    const float* __restrict__ Gin,
    const u16* __restrict__ Whh16f, const u16* __restrict__ Whh16b,
    const float* __restrict__ h0, const float* __restrict__ c0,
    float* __restrict__ hs, unsigned long long* __restrict__ htag,
    float* __restrict__ cbuf, int t0, int CT)
{
    const int wg = blockIdx.x;            // 512 WGs
    const int w = wg >> 5;                // member 0..15: ees [16w, +16)
    const int g = wg & 31;
    const int dir   = g >> 4;
    const int bbase = (g & 15) << 2;
    const int tid = threadIdx.x;
    const int ks = tid & 15;              // k-slice: halves [16ks,+16)
    const int ep = tid >> 4;              // which ee of the member's 16
    const int ee = w * 16 + ep;
    const int P0 = ks & 1, P1 = (ks >> 1) & 1;
    const int bloc = ks & 3;              // batch this thread finalizes
    const u16* __restrict__ Whh16 = dir ? Whh16b : Whh16f;

    __shared__ unsigned int Wl[256 * 33];     // 33,792 B private blocks
    __shared__ unsigned int Hd[2][4][192];    // 6,144 B swizzled h

    const int wbase = tid * 33;

    // ---- one-time weight stage: 8 uint4 = rows {q*256+ee} dwords [8ks,+8)
#pragma unroll
    for (int q = 0; q < 4; q++) {
        const unsigned int* wp =
            (const unsigned int*)(Whh16 + (size_t)(q * 256 + ee) * HID);
#pragma unroll
        for (int i2 = 0; i2 < 2; i2++)
            *(uint4*)&Wl[wbase + (q * 2 + i2) * 4] =
                *(const uint4*)(wp + 8 * ks + 4 * i2);
    }

    float c = ((t0 == 0) ? c0 : cbuf)
        [((size_t)dir * BATCH + bbase + bloc) * HID + ee];

    const int sb = tid >> 6, k4 = tid & 63;   // staging: batch=wave, f4-slot
    const int soff = 12 * (k4 >> 2) + 2 * (k4 & 3);

    const float4* __restrict__ G4 = (const float4*)Gin;
    const size_t gbase = (size_t)dir * CT * 16384
                       + (size_t)(bbase + bloc) * 256 + ee;
    float4 gv = G4[gbase];                    // t_local = 0

    __syncthreads();                          // weights staged

    for (int t = t0; t < t0 + CT; t++) {
        const int wslot = t & 1;

        // prefetch Gin for t+1 (overlaps the poll)
        int tln = t + 1 - t0; if (tln >= CT) tln = CT - 1;
        const float4 gvn = G4[gbase + (size_t)tln * 16384];

        // ---- stage h(t-1): poll tagged data, pack fp16, swizzled write ---
        {
            float4 hv;
            if (t == 0) {
                hv = ((const float4*)(h0
                    + ((size_t)dir * BATCH + bbase + sb) * HID))[k4];
            } else {
                const unsigned long long* hp =
                    htag + ((((size_t)((t - 1) & 1) * 2 + dir) * BATCH + bbase + sb) * HID
                            + k4 * 4);
                const unsigned int tg = (unsigned int)t;
                unsigned long long u0, u1, u2, u3;
                for (;;) {
                    u0 = __hip_atomic_load(hp + 0, __ATOMIC_RELAXED, __HIP_MEMORY_SCOPE_AGENT);
                    u1 = __hip_atomic_load(hp + 1, __ATOMIC_RELAXED, __HIP_MEMORY_SCOPE_AGENT);
                    u2 = __hip_atomic_load(hp + 2, __ATOMIC_RELAXED, __HIP_MEMORY_SCOPE_AGENT);
                    u3 = __hip_atomic_load(hp + 3, __ATOMIC_RELAXED, __HIP_MEMORY_SCOPE_AGENT);
                    if (((unsigned int)(u0 >> 32) == tg) & ((unsigned int)(u1 >> 32) == tg) &
                        ((unsigned int)(u2 >> 32) == tg) & ((unsigned int)(u3 >> 32) == tg))
                        break;
                    __builtin_amdgcn_s_sleep(1);
                }
                hv.x = __uint_as_float((unsigned int)u0);
                hv.y = __uint_as_float((unsigned int)u1);
                hv.z = __uint_as_float((unsigned int)u2);
                hv.w = __uint_as_float((unsigned int)u3);
            }
            uint2 hp2;
            hp2.x = __builtin_bit_cast(unsigned int, (h2){(_Float16)hv.x, (_Float16)hv.y});
            hp2.y = __builtin_bit_cast(unsigned int, (h2){(_Float16)hv.z, (_Float16)hv.w});
            *(uint2*)&Hd[wslot][sb][soff] = hp2;
        }
        __syncthreads();

        // ---- fp16 dot2 GEMV: 4 rows x 4 batches x 16 k ----
        float a[4][4];
#pragma unroll
        for (int q = 0; q < 4; q++)
#pragma unroll
            for (int b = 0; b < 4; b++) a[q][b] = 0.f;

#pragma unroll
        for (int i2 = 0; i2 < 2; i2++) {
            uint4 h4[4];
#pragma unroll
            for (int b = 0; b < 4; b++)
                h4[b] = *(const uint4*)&Hd[wslot][b][12 * ks + 4 * i2];
#pragma unroll
            for (int q = 0; q < 4; q++) {
                const uint4 w4 = *(const uint4*)&Wl[wbase + (q * 2 + i2) * 4];
#pragma unroll
                for (int b = 0; b < 4; b++) {
                    a[q][b] = dot2_f16(w4.x, h4[b].x, a[q][b]);
                    a[q][b] = dot2_f16(w4.y, h4[b].y, a[q][b]);
                    a[q][b] = dot2_f16(w4.z, h4[b].z, a[q][b]);
                    a[q][b] = dot2_f16(w4.w, h4[b].w, a[q][b]);
                }
            }
        }

        // ---- reduce: xor1/xor2 scatter b, xor4/xor8 allreduce ----
        float n[4];
#pragma unroll
        for (int q = 0; q < 4; q++) {
            float sA = P0 ? a[q][0] : a[q][1];
            float sB = P0 ? a[q][2] : a[q][3];
            float m0 = (P0 ? a[q][1] : a[q][0]) + __shfl_xor(sA, 1, 64);
            float m1 = (P0 ? a[q][3] : a[q][2]) + __shfl_xor(sB, 1, 64);
            float s2 = P1 ? m0 : m1;
            float nn = (P1 ? m1 : m0) + __shfl_xor(s2, 2, 64);
            nn += __shfl_xor(nn, 4, 64);
            nn += __shfl_xor(nn, 8, 64);
            n[q] = nn;
        }

        // ---- cell update for (ee, b = bbase+bloc), 4x replicated ----
        const float x0 = n[0] + gv.x;   // i
        const float x1 = n[1] + gv.y;   // f
        const float x2 = n[2] + gv.z;   // g
        const float x3 = n[3] + gv.w;   // o
        c = (1.f / (1.f + expf(-x1))) * c + (1.f / (1.f + expf(-x0))) * tanhf(x2);
        const float h = (1.f / (1.f + expf(-x3))) * tanhf(c);
        gv = gvn;

        if (ks < 4) {
            const int t_orig = dir ? (LSEQ - 1 - t) : t;
            const unsigned long long pkt =
                ((unsigned long long)(unsigned int)(t + 1) << 32)
                | (unsigned long long)__float_as_uint(h);
            __hip_atomic_store(
                &htag[(((size_t)wslot * 2 + dir) * BATCH + bbase + ks) * HID + ee],
                pkt, __ATOMIC_RELAXED, __HIP_MEMORY_SCOPE_AGENT);
            hs[((size_t)(dir * LSEQ + t_orig) * BATCH + bbase + ks) * HID + ee] = h;
        }
    }
    if (ks < 4)
        cbuf[((size_t)dir * BATCH + bbase + ks) * HID + ee] = c;
}

// ---------------- output projection: logits[b][t][11] ----------------
__global__ void __launch_bounds__(256) logits_k(
    const float* __restrict__ hs, const float* __restrict__ Wout,
    const float* __restrict__ bout, float* __restrict__ logits)
{
    const int tid = threadIdx.x;
    const int rt = tid >> 4, tg = tid & 15;
    __shared__ float hrow[16][516];
    __shared__ float Wl[NTAG][516];
    const int rbase = blockIdx.x * 16;

#pragma unroll
    for (int i = 0; i < 8; i++) {
        int u  = tid + i * 256;
        int rr = u >> 7, c4 = u & 127;
        int r_g = rbase + rr;
        int b = r_g >> 9, t = r_g & 511;
        int d = (c4 >= 64) ? 1 : 0, k4 = c4 & 63;
        float4 hv = ((const float4*)hs)[(((size_t)d * LSEQ + t) * BATCH + b) * 64 + k4];
        *(float4*)&hrow[rr][c4 * 4] = hv;
    }
    for (int u = tid; u < NTAG * 128; u += 256) {
        int row = u >> 7, c4 = u & 127;
        float4 wv = ((const float4*)Wout)[(size_t)row * 128 + c4];
        *(float4*)&Wl[row][c4 * 4] = wv;
    }
    __syncthreads();

    if (tg < NTAG) {
        const float4* hp = (const float4*)&hrow[rt][0];
        const float4* wp = (const float4*)&Wl[tg][0];
        float acc = 0.f;
#pragma unroll 4
        for (int k = 0; k < 128; k++) {
            float4 h = hp[k], ww = wp[k];
            acc = fmaf(h.x, ww.x, acc); acc = fmaf(h.y, ww.y, acc);
            acc = fmaf(h.z, ww.z, acc); acc = fmaf(h.w, ww.w, acc);
        }
        int r_g = rbase + rt;
        logits[(size_t)r_g * NTAG + tg] = acc + bout[tg];
    }
}

// ---------------- Viterbi (one wave per batch element) ----------------
__global__ void __launch_bounds__(64) viterbi_k(
    const float* __restrict__ logits, const float* __restrict__ trans,
    float* __restrict__ out)
{
    const int b = blockIdx.x, lane = threadIdx.x;
    __shared__ float lgl[LSEQ * NTAG];
    __shared__ unsigned char bp[LSEQ][16];
    __shared__ float pathf[LSEQ];

    {
        const float4* src = (const float4*)(logits + (size_t)b * LSEQ * NTAG);
        float4* dst = (float4*)lgl;
        for (int u = lane; u < (LSEQ * NTAG) / 4; u += 64) dst[u] = src[u];
    }
    float tcol[NTAG];
    if (lane < NTAG) {
#pragma unroll
        for (int i = 0; i < NTAG; i++) tcol[i] = trans[i * NTAG + lane];
    }
    __syncthreads();

    float v = (lane < NTAG) ? lgl[lane] : -1e30f;
    for (int t = 1; t < LSEQ; t++) {
        float best = -1e30f; int bi = 0;
#pragma unroll
        for (int i = 0; i < NTAG; i++) {
            float vi = __shfl(v, i, 64) + tcol[i];
            if (vi > best) { best = vi; bi = i; }   // strict > == first-max
        }
        if (lane < NTAG) {
            v = lgl[t * NTAG + lane] + best;
            bp[t][lane] = (unsigned char)bi;
        }
    }
    float bestv = -1e30f; int bestj = 0;
#pragma unroll
    for (int j = 0; j < NTAG; j++) {
        float vj = __shfl(v, j, 64);
        if (vj > bestv) { bestv = vj; bestj = j; }
    }
    if (lane == 0) {
        out[b] = bestv;
        int st = bestj;
        pathf[LSEQ - 1] = (float)st;
        for (int t = LSEQ - 1; t >= 1; t--) { st = bp[t][st]; pathf[t - 1] = (float)st; }
    }
    __syncthreads();
    for (int t = lane; t < LSEQ; t += 64)
        out[BATCH + (size_t)b * LSEQ + t] = pathf[t];
}

// ---------------- host ----------------
extern "C" void kernel_launch(void* const* d_in, const int* in_sizes, int n_in,
                              void* d_out, int out_size, void* d_ws, size_t ws_size,
                              hipStream_t stream)
{
    (void)in_sizes; (void)n_in; (void)out_size;
    const int*   sent  = (const int*)  d_in[0];
    const float* emb   = (const float*)d_in[1];
    const float* Wihf  = (const float*)d_in[2];
    const float* Whhf  = (const float*)d_in[3];
    const float* bf    = (const float*)d_in[4];
    const float* Wihb  = (const float*)d_in[5];
    const float* Whhb  = (const float*)d_in[6];
    const float* bb    = (const float*)d_in[7];
    const float* Wout  = (const float*)d_in[8];
    const float* bout  = (const float*)d_in[9];
    const float* trans = (const float*)d_in[10];
    const float* h0    = (const float*)d_in[11];
    const float* c0    = (const float*)d_in[12];
    float* out = (float*)d_out;

    // ws (floats): Gin[CT*131072] | hs[16777216] | htag[262144] | cbuf[32768]
    //  | logits[360448] | embb[4096000] | w16f[131072] | w16b[131072]
    //  | whh16f[131072] | whh16b[131072]
    const size_t fixed = 16777216ull + 262144ull + 32768ull + 360448ull
                       + 4096000ull + 131072ull + 131072ull
                       + 131072ull + 131072ull;
    int CT = LSEQ;
    while (CT > 8 && ((size_t)CT * 131072ull + fixed) * 4ull > ws_size) CT >>= 1;

    float* ws = (float*)d_ws;
    size_t off = 0;
    float* Gin  = ws + off; off += (size_t)CT * 131072ull;
    float* hs   = ws + off; off += 16777216ull;
    unsigned long long* htag = (unsigned long long*)(ws + off); off += 262144ull;
    float* cbuf = ws + off; off += 32768ull;
    float* lgts = ws + off; off += 360448ull;
    u16* embb = (u16*)(ws + off); off += 4096000ull;
    u16* w16f = (u16*)(ws + off); off += 131072ull;
    u16* w16b = (u16*)(ws + off); off += 131072ull;
    u16* whh16f = (u16*)(ws + off); off += 131072ull;
    u16* whh16b = (u16*)(ws + off); off += 131072ull;

    hipLaunchKernelGGL(cvt_bf16, dim3(2048), dim3(256), 0, stream,
                       emb, embb, (32000 * 256) / 4);
    hipLaunchKernelGGL(cvt_bf16, dim3(256), dim3(256), 0, stream,
                       Wihf, w16f, (1024 * 256) / 4);
    hipLaunchKernelGGL(cvt_bf16, dim3(256), dim3(256), 0, stream,
                       Wihb, w16b, (1024 * 256) / 4);
    hipLaunchKernelGGL(cvt_f16, dim3(256), dim3(256), 0, stream,
                       Whhf, whh16f, (1024 * 256) / 4);
    hipLaunchKernelGGL(cvt_f16, dim3(256), dim3(256), 0, stream,
                       Whhb, whh16b, (1024 * 256) / 4);

    const int nch = LSEQ / CT;
    for (int c = 0; c < nch; c++) {
        int t0 = c * CT;
        hipLaunchKernelGGL(gemm_in, dim3(CT / 2, 8, 2), dim3(256), 0, stream,
                           sent, embb, w16f, w16b, bf, bb, Gin, t0, CT);
        hipLaunchKernelGGL(lstm_rec, dim3(512), dim3(256), 0, stream,
                           Gin, whh16f, whh16b, h0, c0, hs, htag, cbuf, t0, CT);
    }
    hipLaunchKernelGGL(logits_k, dim3((BATCH * LSEQ) / 16), dim3(256), 0, stream,
                       hs, Wout, bout, lgts);
    hipLaunchKernelGGL(viterbi_k, dim3(BATCH), dim3(64), 0, stream,
                       lgts, trans, out);
}

// Round 7
// 2312.843 us; speedup vs baseline: 1.9247x; 1.9247x over previous
//
#include <hip/hip_runtime.h>
#include <cstdint>
#include <cstddef>
#include <cstring>

#define LSEQ 512
#define BATCH 64
#define DIM 256
#define HID 256
#define NTAG 11

typedef float vf4 __attribute__((ext_vector_type(4)));
typedef __bf16 bf16x8 __attribute__((ext_vector_type(8)));
typedef float f32x4 __attribute__((ext_vector_type(4)));
typedef _Float16 h2 __attribute__((ext_vector_type(2)));
typedef unsigned short u16;

static __device__ __forceinline__ float dot2_f16(unsigned int w, unsigned int h, float acc)
{
#if __has_builtin(__builtin_amdgcn_fdot2)
    return __builtin_amdgcn_fdot2(__builtin_bit_cast(h2, w),
                                  __builtin_bit_cast(h2, h), acc, false);
#else
    h2 a = __builtin_bit_cast(h2, w), b = __builtin_bit_cast(h2, h);
    acc = fmaf((float)a.x, (float)b.x, acc);
    return fmaf((float)a.y, (float)b.y, acc);
#endif
}

// ---------------- fp32 -> bf16 (RNE) convert ----------------
__global__ void __launch_bounds__(256) cvt_bf16(
    const float* __restrict__ src, u16* __restrict__ dst, int n4)
{
    int i = blockIdx.x * blockDim.x + threadIdx.x;
    const int stride = gridDim.x * blockDim.x;
    for (; i < n4; i += stride) {
        float4 f = ((const float4*)src)[i];
        ushort4 r;
        unsigned int u;
        u = __float_as_uint(f.x); u += 0x7FFFu + ((u >> 16) & 1u); r.x = (u16)(u >> 16);
        u = __float_as_uint(f.y); u += 0x7FFFu + ((u >> 16) & 1u); r.y = (u16)(u >> 16);
        u = __float_as_uint(f.z); u += 0x7FFFu + ((u >> 16) & 1u); r.z = (u16)(u >> 16);
        u = __float_as_uint(f.w); u += 0x7FFFu + ((u >> 16) & 1u); r.w = (u16)(u >> 16);
        ((ushort4*)dst)[i] = r;
    }
}

// ---------------- fp32 -> fp16 (RNE) convert ----------------
__global__ void __launch_bounds__(256) cvt_f16(
    const float* __restrict__ src, u16* __restrict__ dst, int n4)
{
    int i = blockIdx.x * blockDim.x + threadIdx.x;
    const int stride = gridDim.x * blockDim.x;
    for (; i < n4; i += stride) {
        float4 f = ((const float4*)src)[i];
        ushort4 r;
        r.x = __builtin_bit_cast(u16, (_Float16)f.x);
        r.y = __builtin_bit_cast(u16, (_Float16)f.y);
        r.z = __builtin_bit_cast(u16, (_Float16)f.z);
        r.w = __builtin_bit_cast(u16, (_Float16)f.w);
        ((ushort4*)dst)[i] = r;
    }
}

// ---------------- input GEMM via bf16 MFMA (+gather, +bias) ----------------
__global__ void __launch_bounds__(256) gemm_in(
    const int* __restrict__ sent, const u16* __restrict__ embb,
    const u16* __restrict__ w16f, const u16* __restrict__ w16b,
    const float* __restrict__ bf_, const float* __restrict__ bb_,
    float* __restrict__ Gin, int t0, int CT)
{
    const int mtile = blockIdx.x, ntile = blockIdx.y, dir = blockIdx.z;
    const u16* __restrict__ W16 = dir ? w16b : w16f;
    const float* __restrict__ bias = dir ? bb_ : bf_;
    const int tid = threadIdx.x;
    const int wave = tid >> 6, lane = tid & 63;
    const int wm = wave & 1, wn = wave >> 1;

    __shared__ u16 Asm[128][40];   // [m][k] pitch 40 (2-way max on frag reads)
    __shared__ u16 Bsm[128][40];   // [n][k]

    const int row = tid >> 1, half = tid & 1;
    const u16* ap;
    {
        int m_g = mtile * 128 + row;
        int tl = m_g >> 6, b = m_g & 63;
        int tg = t0 + tl;
        int tt = dir ? (LSEQ - 1 - tg) : tg;
        ap = embb + (size_t)sent[b * LSEQ + tt] * DIM;
    }
    const u16* bp = W16 + (size_t)(ntile * 128 + row) * DIM;

    f32x4 acc[4][4];
#pragma unroll
    for (int i = 0; i < 4; i++)
#pragma unroll
        for (int j = 0; j < 4; j++) acc[i][j] = (f32x4){0.f, 0.f, 0.f, 0.f};

    const int col = lane & 15, quad = lane >> 4;

    for (int ki = 0; ki < 8; ki++) {
        const int k0 = ki * 32;
        __syncthreads();
        {
            uint4 a0 = *(const uint4*)(ap + k0 + half * 16);
            uint4 a1 = *(const uint4*)(ap + k0 + half * 16 + 8);
            uint4 b0 = *(const uint4*)(bp + k0 + half * 16);
            uint4 b1 = *(const uint4*)(bp + k0 + half * 16 + 8);
            *(uint4*)&Asm[row][half * 16 + 0] = a0;
            *(uint4*)&Asm[row][half * 16 + 8] = a1;
            *(uint4*)&Bsm[row][half * 16 + 0] = b0;
            *(uint4*)&Bsm[row][half * 16 + 8] = b1;
        }
        __syncthreads();

        bf16x8 af[4], bg[4];
#pragma unroll
        for (int i = 0; i < 4; i++) {
            af[i] = *(const bf16x8*)&Asm[wm * 64 + i * 16 + col][quad * 8];
            bg[i] = *(const bf16x8*)&Bsm[wn * 64 + i * 16 + col][quad * 8];
        }
#pragma unroll
        for (int mt = 0; mt < 4; mt++)
#pragma unroll
            for (int nt = 0; nt < 4; nt++)
                acc[mt][nt] = __builtin_amdgcn_mfma_f32_16x16x32_bf16(
                    af[mt], bg[nt], acc[mt][nt], 0, 0, 0);
    }

#pragma unroll
    for (int nt = 0; nt < 4; nt++) {
        const int n_g = ntile * 128 + wn * 64 + nt * 16 + col;
        const float bv = bias[n_g];
        const int q = n_g >> 8, e = n_g & 255;
#pragma unroll
        for (int mt = 0; mt < 4; mt++)
#pragma unroll
            for (int r = 0; r < 4; r++) {
                const int m_g = mtile * 128 + wm * 64 + mt * 16 + quad * 4 + r;
                const int tl = m_g >> 6, b = m_g & 63;
                Gin[(((size_t)(dir * CT + tl) * 64 + b) * 256 + e) * 4 + q]
                    = acc[mt][nt][r] + bv;
            }
    }
}

// ---------------- persistent bidirectional LSTM recurrence ------
// r5 (M=8, 845us) vs r6 (M=16, 2300us): exchange cost is SUPER-LINEAR in
// member count (poll sweeps, publish fan-in, skew); compute is cheap.
// => M=4: 128 WGs = 32 groups x 4 members; member w owns 64 ees.
// Weights: 4 gates x 64 ees x 256 k fp16 = 128 KB -> LDS-resident
// (132 KB with pitch-129 private blocks; bank = (tid+4s) mod 32 = free
// 2-way).  Chip-wide poll traffic HALVES vs r5; per-thread compute
// doubles to 512 dot2 (~1000 cyc VALU) - deliberate trade.
// Thread (ep = tid>>4, ks = tid&15): computes rows {q*256 + 64w+4ep+e4},
// e4 = 0..3, k-halves [16ks,+16), 4 batches -> 64 accs.
// Reduce = 4-stage butterfly SCATTER: xor1/xor2 scatter batch bits
// (b = ks&3), xor4/xor8 scatter e4 bits (e4 = ks>>2) => EVERY lane lands
// the full 4-gate sum for exactly one (ee = 64w+4ep+(ks>>2),
// b = bbase+(ks&3)): no replication, no divergent cell update, no
// dynamic register indexing.  h-exchange (tag-in-data 64-bit agent
// atomics, Hd pitch-12 swizzle) identical to r5.
__global__ void __launch_bounds__(256, 1) lstm_rec(
    const float* __restrict__ Gin,
    const u16* __restrict__ Whh16f, const u16* __restrict__ Whh16b,
    const float* __restrict__ h0, const float* __restrict__ c0,
    float* __restrict__ hs, unsigned long long* __restrict__ htag,
    float* __restrict__ cbuf, int t0, int CT)
{
    const int wg = blockIdx.x;            // 128 WGs
    const int w = wg >> 5;                // member 0..3: ees [64w, +64)
    const int g = wg & 31;
    const int dir   = g >> 4;
    const int bbase = (g & 15) << 2;
    const int tid = threadIdx.x;
    const int ks = tid & 15;              // k-slice: halves [16ks,+16)
    const int ep = tid >> 4;              // ee-quad index 0..15
    const int P0 = ks & 1, P1 = (ks >> 1) & 1;
    const int P2 = (ks >> 2) & 1, P3 = ks >> 3;
    const int bloc = ks & 3;              // batch this thread finalizes
    const int e4sel = ks >> 2;            // which e4 this thread finalizes
    const int eef = w * 64 + 4 * ep + e4sel;
    const u16* __restrict__ Whh16 = dir ? Whh16b : Whh16f;

    __shared__ unsigned int Wl[256 * 129];    // 132,096 B private blocks
    __shared__ unsigned int Hd[2][4][192];    // 6,144 B swizzled h

    const int wbase = tid * 129;

    // ---- one-time weight stage: 32 uint4 = rows {q*256 + 64w+4ep+e4},
    //      dwords [8ks,+8)
#pragma unroll
    for (int e4 = 0; e4 < 4; e4++)
#pragma unroll
        for (int q = 0; q < 4; q++) {
            const unsigned int* wp = (const unsigned int*)
                (Whh16 + (size_t)(q * 256 + w * 64 + 4 * ep + e4) * HID);
#pragma unroll
            for (int i2 = 0; i2 < 2; i2++)
                *(uint4*)&Wl[wbase + ((e4 * 4 + q) * 2 + i2) * 4] =
                    *(const uint4*)(wp + 8 * ks + 4 * i2);
        }

    float c = ((t0 == 0) ? c0 : cbuf)
        [((size_t)dir * BATCH + bbase + bloc) * HID + eef];

    const int sb = tid >> 6, k4 = tid & 63;   // staging: batch=wave, f4-slot
    const int soff = 12 * (k4 >> 2) + 2 * (k4 & 3);

    const float4* __restrict__ G4 = (const float4*)Gin;
    const size_t gbase = (size_t)dir * CT * 16384
                       + (size_t)(bbase + bloc) * 256 + eef;
    float4 gv = G4[gbase];                    // t_local = 0

    __syncthreads();                          // weights staged

    for (int t = t0; t < t0 + CT; t++) {
        const int wslot = t & 1;

        // prefetch Gin for t+1 (overlaps the poll)
        int tln = t + 1 - t0; if (tln >= CT) tln = CT - 1;
        const float4 gvn = G4[gbase + (size_t)tln * 16384];

        // ---- stage h(t-1): poll tagged data, pack fp16, swizzled write ---
        {
            float4 hv;
            if (t == 0) {
                hv = ((const float4*)(h0
                    + ((size_t)dir * BATCH + bbase + sb) * HID))[k4];
            } else {
                const unsigned long long* hp =
                    htag + ((((size_t)((t - 1) & 1) * 2 + dir) * BATCH + bbase + sb) * HID
                            + k4 * 4);
                const unsigned int tg = (unsigned int)t;
                unsigned long long u0, u1, u2, u3;
                for (;;) {
                    u0 = __hip_atomic_load(hp + 0, __ATOMIC_RELAXED, __HIP_MEMORY_SCOPE_AGENT);
                    u1 = __hip_atomic_load(hp + 1, __ATOMIC_RELAXED, __HIP_MEMORY_SCOPE_AGENT);
                    u2 = __hip_atomic_load(hp + 2, __ATOMIC_RELAXED, __HIP_MEMORY_SCOPE_AGENT);
                    u3 = __hip_atomic_load(hp + 3, __ATOMIC_RELAXED, __HIP_MEMORY_SCOPE_AGENT);
                    if (((unsigned int)(u0 >> 32) == tg) & ((unsigned int)(u1 >> 32) == tg) &
                        ((unsigned int)(u2 >> 32) == tg) & ((unsigned int)(u3 >> 32) == tg))
                        break;
                    __builtin_amdgcn_s_sleep(1);
                }
                hv.x = __uint_as_float((unsigned int)u0);
                hv.y = __uint_as_float((unsigned int)u1);
                hv.z = __uint_as_float((unsigned int)u2);
                hv.w = __uint_as_float((unsigned int)u3);
            }
            uint2 hp2;
            hp2.x = __builtin_bit_cast(unsigned int, (h2){(_Float16)hv.x, (_Float16)hv.y});
            hp2.y = __builtin_bit_cast(unsigned int, (h2){(_Float16)hv.z, (_Float16)hv.w});
            *(uint2*)&Hd[wslot][sb][soff] = hp2;
        }
        __syncthreads();

        // ---- fp16 dot2 GEMV: 16 rows x 4 batches x 16 k ----
        float a[4][4][4];                     // [e4][q][b]
#pragma unroll
        for (int e4 = 0; e4 < 4; e4++)
#pragma unroll
            for (int q = 0; q < 4; q++)
#pragma unroll
                for (int b = 0; b < 4; b++) a[e4][q][b] = 0.f;

#pragma unroll
        for (int i2 = 0; i2 < 2; i2++) {
            uint4 h4[4];
#pragma unroll
            for (int b = 0; b < 4; b++)
                h4[b] = *(const uint4*)&Hd[wslot][b][12 * ks + 4 * i2];
#pragma unroll
            for (int e4 = 0; e4 < 4; e4++)
#pragma unroll
                for (int q = 0; q < 4; q++) {
                    const uint4 w4 =
                        *(const uint4*)&Wl[wbase + ((e4 * 4 + q) * 2 + i2) * 4];
#pragma unroll
                    for (int b = 0; b < 4; b++) {
                        a[e4][q][b] = dot2_f16(w4.x, h4[b].x, a[e4][q][b]);
                        a[e4][q][b] = dot2_f16(w4.y, h4[b].y, a[e4][q][b]);
                        a[e4][q][b] = dot2_f16(w4.z, h4[b].z, a[e4][q][b]);
                        a[e4][q][b] = dot2_f16(w4.w, h4[b].w, a[e4][q][b]);
                    }
                }
        }

        // ---- 4-stage butterfly scatter: xor1/xor2 -> batch, xor4/xor8 -> e4
        float n[4];
#pragma unroll
        for (int q = 0; q < 4; q++) {
            float r[4];
#pragma unroll
            for (int e4 = 0; e4 < 4; e4++) {
                float sA = P0 ? a[e4][q][0] : a[e4][q][1];
                float sB = P0 ? a[e4][q][2] : a[e4][q][3];
                float m0 = (P0 ? a[e4][q][1] : a[e4][q][0]) + __shfl_xor(sA, 1, 64);
                float m1 = (P0 ? a[e4][q][3] : a[e4][q][2]) + __shfl_xor(sB, 1, 64);
                float s2 = P1 ? m0 : m1;
                r[e4] = (P1 ? m1 : m0) + __shfl_xor(s2, 2, 64);
            }
            float s01 = P2 ? r[0] : r[1];
            float s23 = P2 ? r[2] : r[3];
            float t0r = (P2 ? r[1] : r[0]) + __shfl_xor(s01, 4, 64);
            float t1r = (P2 ? r[3] : r[2]) + __shfl_xor(s23, 4, 64);
            float s3 = P3 ? t0r : t1r;
            n[q] = (P3 ? t1r : t0r) + __shfl_xor(s3, 8, 64);
        }

        // ---- cell update for (eef, b = bbase+bloc) ----
        const float x0 = n[0] + gv.x;   // i
        const float x1 = n[1] + gv.y;   // f
        const float x2 = n[2] + gv.z;   // g
        const float x3 = n[3] + gv.w;   // o
        c = (1.f / (1.f + expf(-x1))) * c + (1.f / (1.f + expf(-x0))) * tanhf(x2);
        const float h = (1.f / (1.f + expf(-x3))) * tanhf(c);
        gv = gvn;

        {
            const int t_orig = dir ? (LSEQ - 1 - t) : t;
            const unsigned long long pkt =
                ((unsigned long long)(unsigned int)(t + 1) << 32)
                | (unsigned long long)__float_as_uint(h);
            __hip_atomic_store(
                &htag[(((size_t)wslot * 2 + dir) * BATCH + bbase + bloc) * HID + eef],
                pkt, __ATOMIC_RELAXED, __HIP_MEMORY_SCOPE_AGENT);
            hs[((size_t)(dir * LSEQ + t_orig) * BATCH + bbase + bloc) * HID + eef] = h;
        }
    }
    cbuf[((size_t)dir * BATCH + bbase + bloc) * HID + eef] = c;
}

// ---------------- output projection: logits[b][t][11] ----------------
__global__ void __launch_bounds__(256) logits_k(
    const float* __restrict__ hs, const float* __restrict__ Wout,
    const float* __restrict__ bout, float* __restrict__ logits)
{
    const int tid = threadIdx.x;
    const int rt = tid >> 4, tg = tid & 15;
    __shared__ float hrow[16][516];
    __shared__ float Wl[NTAG][516];
    const int rbase = blockIdx.x * 16;

#pragma unroll
    for (int i = 0; i < 8; i++) {
        int u  = tid + i * 256;
        int rr = u >> 7, c4 = u & 127;
        int r_g = rbase + rr;
        int b = r_g >> 9, t = r_g & 511;
        int d = (c4 >= 64) ? 1 : 0, k4 = c4 & 63;
        float4 hv = ((const float4*)hs)[(((size_t)d * LSEQ + t) * BATCH + b) * 64 + k4];
        *(float4*)&hrow[rr][c4 * 4] = hv;
    }
    for (int u = tid; u < NTAG * 128; u += 256) {
        int row = u >> 7, c4 = u & 127;
        float4 wv = ((const float4*)Wout)[(size_t)row * 128 + c4];
        *(float4*)&Wl[row][c4 * 4] = wv;
    }
    __syncthreads();

    if (tg < NTAG) {
        const float4* hp = (const float4*)&hrow[rt][0];
        const float4* wp = (const float4*)&Wl[tg][0];
        float acc = 0.f;
#pragma unroll 4
        for (int k = 0; k < 128; k++) {
            float4 h = hp[k], ww = wp[k];
            acc = fmaf(h.x, ww.x, acc); acc = fmaf(h.y, ww.y, acc);
            acc = fmaf(h.z, ww.z, acc); acc = fmaf(h.w, ww.w, acc);
        }
        int r_g = rbase + rt;
        logits[(size_t)r_g * NTAG + tg] = acc + bout[tg];
    }
}

// ---------------- Viterbi (one wave per batch element) ----------------
__global__ void __launch_bounds__(64) viterbi_k(
    const float* __restrict__ logits, const float* __restrict__ trans,
    float* __restrict__ out)
{
    const int b = blockIdx.x, lane = threadIdx.x;
    __shared__ float lgl[LSEQ * NTAG];
    __shared__ unsigned char bp[LSEQ][16];
    __shared__ float pathf[LSEQ];

    {
        const float4* src = (const float4*)(logits + (size_t)b * LSEQ * NTAG);
        float4* dst = (float4*)lgl;
        for (int u = lane; u < (LSEQ * NTAG) / 4; u += 64) dst[u] = src[u];
    }
    float tcol[NTAG];
    if (lane < NTAG) {
#pragma unroll
        for (int i = 0; i < NTAG; i++) tcol[i] = trans[i * NTAG + lane];
    }
    __syncthreads();

    float v = (lane < NTAG) ? lgl[lane] : -1e30f;
    for (int t = 1; t < LSEQ; t++) {
        float best = -1e30f; int bi = 0;
#pragma unroll
        for (int i = 0; i < NTAG; i++) {
            float vi = __shfl(v, i, 64) + tcol[i];
            if (vi > best) { best = vi; bi = i; }   // strict > == first-max
        }
        if (lane < NTAG) {
            v = lgl[t * NTAG + lane] + best;
            bp[t][lane] = (unsigned char)bi;
        }
    }
    float bestv = -1e30f; int bestj = 0;
#pragma unroll
    for (int j = 0; j < NTAG; j++) {
        float vj = __shfl(v, j, 64);
        if (vj > bestv) { bestv = vj; bestj = j; }
    }
    if (lane == 0) {
        out[b] = bestv;
        int st = bestj;
        pathf[LSEQ - 1] = (float)st;
        for (int t = LSEQ - 1; t >= 1; t--) { st = bp[t][st]; pathf[t - 1] = (float)st; }
    }
    __syncthreads();
    for (int t = lane; t < LSEQ; t += 64)
        out[BATCH + (size_t)b * LSEQ + t] = pathf[t];
}

// ---------------- host ----------------
extern "C" void kernel_launch(void* const* d_in, const int* in_sizes, int n_in,
                              void* d_out, int out_size, void* d_ws, size_t ws_size,
                              hipStream_t stream)
{
    (void)in_sizes; (void)n_in; (void)out_size;
    const int*   sent  = (const int*)  d_in[0];
    const float* emb   = (const float*)d_in[1];
    const float* Wihf  = (const float*)d_in[2];
    const float* Whhf  = (const float*)d_in[3];
    const float* bf    = (const float*)d_in[4];
    const float* Wihb  = (const float*)d_in[5];
    const float* Whhb  = (const float*)d_in[6];
    const float* bb    = (const float*)d_in[7];
    const float* Wout  = (const float*)d_in[8];
    const float* bout  = (const float*)d_in[9];
    const float* trans = (const float*)d_in[10];
    const float* h0    = (const float*)d_in[11];
    const float* c0    = (const float*)d_in[12];
    float* out = (float*)d_out;

    // ws (floats): Gin[CT*131072] | hs[16777216] | htag[262144] | cbuf[32768]
    //  | logits[360448] | embb[4096000] | w16f[131072] | w16b[131072]
    //  | whh16f[131072] | whh16b[131072]
    const size_t fixed = 16777216ull + 262144ull + 32768ull + 360448ull
                       + 4096000ull + 131072ull + 131072ull
                       + 131072ull + 131072ull;
    int CT = LSEQ;
    while (CT > 8 && ((size_t)CT * 131072ull + fixed) * 4ull > ws_size) CT >>= 1;

    float* ws = (float*)d_ws;
    size_t off = 0;
    float* Gin  = ws + off; off += (size_t)CT * 131072ull;
    float* hs   = ws + off; off += 16777216ull;
    unsigned long long* htag = (unsigned long long*)(ws + off); off += 262144ull;
    float* cbuf = ws + off; off += 32768ull;
    float* lgts = ws + off; off += 360448ull;
    u16* embb = (u16*)(ws + off); off += 4096000ull;
    u16* w16f = (u16*)(ws + off); off += 131072ull;
    u16* w16b = (u16*)(ws + off); off += 131072ull;
    u16* whh16f = (u16*)(ws + off); off += 131072ull;
    u16* whh16b = (u16*)(ws + off); off += 131072ull;

    hipLaunchKernelGGL(cvt_bf16, dim3(2048), dim3(256), 0, stream,
                       emb, embb, (32000 * 256) / 4);
    hipLaunchKernelGGL(cvt_bf16, dim3(256), dim3(256), 0, stream,
                       Wihf, w16f, (1024 * 256) / 4);
    hipLaunchKernelGGL(cvt_bf16, dim3(256), dim3(256), 0, stream,
                       Wihb, w16b, (1024 * 256) / 4);
    hipLaunchKernelGGL(cvt_f16, dim3(256), dim3(256), 0, stream,
                       Whhf, whh16f, (1024 * 256) / 4);
    hipLaunchKernelGGL(cvt_f16, dim3(256), dim3(256), 0, stream,
                       Whhb, whh16b, (1024 * 256) / 4);

    const int nch = LSEQ / CT;
    for (int c = 0; c < nch; c++) {
        int t0 = c * CT;
        hipLaunchKernelGGL(gemm_in, dim3(CT / 2, 8, 2), dim3(256), 0, stream,
                           sent, embb, w16f, w16b, bf, bb, Gin, t0, CT);
        hipLaunchKernelGGL(lstm_rec, dim3(128), dim3(256), 0, stream,
                           Gin, whh16f, whh16b, h0, c0, hs, htag, cbuf, t0, CT);
    }
    hipLaunchKernelGGL(logits_k, dim3((BATCH * LSEQ) / 16), dim3(256), 0, stream,
                       hs, Wout, bout, lgts);
    hipLaunchKernelGGL(viterbi_k, dim3(BATCH), dim3(64), 0, stream,
                       lgts, trans, out);
}

// Round 8
// 1637.967 us; speedup vs baseline: 2.7178x; 1.4120x over previous
//
#include <hip/hip_runtime.h>
#include <cstdint>
#include <cstddef>
#include <cstring>

#define LSEQ 512
#define BATCH 64
#define DIM 256
#define HID 256
#define NTAG 11

typedef float vf4 __attribute__((ext_vector_type(4)));
typedef __bf16 bf16x8 __attribute__((ext_vector_type(8)));
typedef float f32x4 __attribute__((ext_vector_type(4)));
typedef _Float16 h2 __attribute__((ext_vector_type(2)));
typedef unsigned short u16;

static __device__ __forceinline__ float dot2_f16(unsigned int w, unsigned int h, float acc)
{
#if __has_builtin(__builtin_amdgcn_fdot2)
    return __builtin_amdgcn_fdot2(__builtin_bit_cast(h2, w),
                                  __builtin_bit_cast(h2, h), acc, false);
#else
    h2 a = __builtin_bit_cast(h2, w), b = __builtin_bit_cast(h2, h);
    acc = fmaf((float)a.x, (float)b.x, acc);
    return fmaf((float)a.y, (float)b.y, acc);
#endif
}

// 16B coherent poll load: bypasses L1/L2 (sc0 sc1) so remote XCD publishes
// are visible; single request replaces 4x8B atomic loads (4x fewer L3
// transactions in the poll storm).
static __device__ __forceinline__ uint4 poll_load16(const unsigned int* p)
{
    uint4 v;
    asm volatile("global_load_dwordx4 %0, %1, off sc0 sc1\n"
                 "s_waitcnt vmcnt(0)"
                 : "=&v"(v) : "v"(p) : "memory");
    return v;
}

// ---------------- fp32 -> bf16 (RNE) convert ----------------
__global__ void __launch_bounds__(256) cvt_bf16(
    const float* __restrict__ src, u16* __restrict__ dst, int n4)
{
    int i = blockIdx.x * blockDim.x + threadIdx.x;
    const int stride = gridDim.x * blockDim.x;
    for (; i < n4; i += stride) {
        float4 f = ((const float4*)src)[i];
        ushort4 r;
        unsigned int u;
        u = __float_as_uint(f.x); u += 0x7FFFu + ((u >> 16) & 1u); r.x = (u16)(u >> 16);
        u = __float_as_uint(f.y); u += 0x7FFFu + ((u >> 16) & 1u); r.y = (u16)(u >> 16);
        u = __float_as_uint(f.z); u += 0x7FFFu + ((u >> 16) & 1u); r.z = (u16)(u >> 16);
        u = __float_as_uint(f.w); u += 0x7FFFu + ((u >> 16) & 1u); r.w = (u16)(u >> 16);
        ((ushort4*)dst)[i] = r;
    }
}

// ---------------- fp32 -> fp16 (RNE) convert ----------------
__global__ void __launch_bounds__(256) cvt_f16(
    const float* __restrict__ src, u16* __restrict__ dst, int n4)
{
    int i = blockIdx.x * blockDim.x + threadIdx.x;
    const int stride = gridDim.x * blockDim.x;
    for (; i < n4; i += stride) {
        float4 f = ((const float4*)src)[i];
        ushort4 r;
        r.x = __builtin_bit_cast(u16, (_Float16)f.x);
        r.y = __builtin_bit_cast(u16, (_Float16)f.y);
        r.z = __builtin_bit_cast(u16, (_Float16)f.z);
        r.w = __builtin_bit_cast(u16, (_Float16)f.w);
        ((ushort4*)dst)[i] = r;
    }
}

// ---------------- input GEMM via bf16 MFMA (+gather, +bias) ----------------
// Epilogue writes gate-contiguous fp16 Gin:
//   u16 index (((dir*CT + tl)*64 + b)*256 + e)*4 + q    (n = q*256 + e)
// fp16 Gin halves HBM fetch and lets CT=512 fit the workspace -> ONE
// lstm_rec dispatch (no mid-sequence drain/relaunch).
__global__ void __launch_bounds__(256) gemm_in(
    const int* __restrict__ sent, const u16* __restrict__ embb,
    const u16* __restrict__ w16f, const u16* __restrict__ w16b,
    const float* __restrict__ bf_, const float* __restrict__ bb_,
    u16* __restrict__ Gin, int t0, int CT)
{
    const int mtile = blockIdx.x, ntile = blockIdx.y, dir = blockIdx.z;
    const u16* __restrict__ W16 = dir ? w16b : w16f;
    const float* __restrict__ bias = dir ? bb_ : bf_;
    const int tid = threadIdx.x;
    const int wave = tid >> 6, lane = tid & 63;
    const int wm = wave & 1, wn = wave >> 1;

    __shared__ u16 Asm[128][40];   // [m][k] pitch 40 (2-way max on frag reads)
    __shared__ u16 Bsm[128][40];   // [n][k]

    const int row = tid >> 1, half = tid & 1;
    const u16* ap;
    {
        int m_g = mtile * 128 + row;
        int tl = m_g >> 6, b = m_g & 63;
        int tg = t0 + tl;
        int tt = dir ? (LSEQ - 1 - tg) : tg;
        ap = embb + (size_t)sent[b * LSEQ + tt] * DIM;
    }
    const u16* bp = W16 + (size_t)(ntile * 128 + row) * DIM;

    f32x4 acc[4][4];
#pragma unroll
    for (int i = 0; i < 4; i++)
#pragma unroll
        for (int j = 0; j < 4; j++) acc[i][j] = (f32x4){0.f, 0.f, 0.f, 0.f};

    const int col = lane & 15, quad = lane >> 4;

    for (int ki = 0; ki < 8; ki++) {
        const int k0 = ki * 32;
        __syncthreads();
        {
            uint4 a0 = *(const uint4*)(ap + k0 + half * 16);
            uint4 a1 = *(const uint4*)(ap + k0 + half * 16 + 8);
            uint4 b0 = *(const uint4*)(bp + k0 + half * 16);
            uint4 b1 = *(const uint4*)(bp + k0 + half * 16 + 8);
            *(uint4*)&Asm[row][half * 16 + 0] = a0;
            *(uint4*)&Asm[row][half * 16 + 8] = a1;
            *(uint4*)&Bsm[row][half * 16 + 0] = b0;
            *(uint4*)&Bsm[row][half * 16 + 8] = b1;
        }
        __syncthreads();

        bf16x8 af[4], bg[4];
#pragma unroll
        for (int i = 0; i < 4; i++) {
            af[i] = *(const bf16x8*)&Asm[wm * 64 + i * 16 + col][quad * 8];
            bg[i] = *(const bf16x8*)&Bsm[wn * 64 + i * 16 + col][quad * 8];
        }
#pragma unroll
        for (int mt = 0; mt < 4; mt++)
#pragma unroll
            for (int nt = 0; nt < 4; nt++)
                acc[mt][nt] = __builtin_amdgcn_mfma_f32_16x16x32_bf16(
                    af[mt], bg[nt], acc[mt][nt], 0, 0, 0);
    }

#pragma unroll
    for (int nt = 0; nt < 4; nt++) {
        const int n_g = ntile * 128 + wn * 64 + nt * 16 + col;
        const float bv = bias[n_g];
        const int q = n_g >> 8, e = n_g & 255;
#pragma unroll
        for (int mt = 0; mt < 4; mt++)
#pragma unroll
            for (int r = 0; r < 4; r++) {
                const int m_g = mtile * 128 + wm * 64 + mt * 16 + quad * 4 + r;
                const int tl = m_g >> 6, b = m_g & 63;
                Gin[(((size_t)(dir * CT + tl) * 64 + b) * 256 + e) * 4 + q]
                    = __builtin_bit_cast(u16, (_Float16)(acc[mt][nt][r] + bv));
            }
    }
}

// ---------------- persistent bidirectional LSTM recurrence ------
// Member-count scan complete: M=16: 2300us, M=8: 845us, M=4: 945us — M=8
// minimal; floor ~3.3us/step across ALL compute variants since r0 =>
// EXCHANGE-bound, with poll CONGESTION as the residual suspect (64K
// threads re-loading 32B of htag per RT = multi-TB/s into L3).
// This round: 3 congestion cuts on the r5/M=8 champion structure:
//  (1) 32-bit packed exchange word: (t+1)<<16 | fp16(h).  t<512 fits
//      16-bit tag; consumers already rounded h to fp16 => identical
//      numerics.  Poll bytes AND publish bytes halve.
//  (2) poll = ONE global_load_dwordx4 sc0 sc1 per thread per iteration
//      (4x fewer L3 requests than 4x8B atomic loads).
//  (3) Gin fp16 => CT=512 single dispatch (no drain/relaunch).
// Everything else identical to r5: 256 WGs = 32 groups x 8 members;
// thread (ep = tid>>4, ks = tid&15) owns rows {q*256 + 32w+2ep+e2},
// k-halves [16ks,+16), 4 batches; weights in thread-private LDS blocks
// (pitch 65: bank = (tid+4s) mod 32 = free 2-way); reduce-scatter over
// lane^{1,2,4,8}; ks<8 publishes (ee = 32w+2ep+(ks>>2&1), b = bbase+(ks&3)).
__global__ void __launch_bounds__(256, 1) lstm_rec(
    const u16* __restrict__ Gin,
    const u16* __restrict__ Whh16f, const u16* __restrict__ Whh16b,
    const float* __restrict__ h0, const float* __restrict__ c0,
    float* __restrict__ hs, unsigned int* __restrict__ htag,
    float* __restrict__ cbuf, int t0, int CT)
{
    const int wg = blockIdx.x;
    const int w = wg >> 5, g = wg & 31;
    const int dir   = g >> 4;
    const int bbase = (g & 15) << 2;
    const int tid = threadIdx.x;
    const int ks = tid & 15;            // k-slice index (16 halves = 8 dwords)
    const int ep = tid >> 4;            // ee-pair index 0..15
    const int ebase = w * 32 + ep * 2;  // first of the 2 hidden elems
    const int P0 = ks & 1, P1 = (ks >> 1) & 1, P2 = (ks >> 2) & 1;
    const int bloc = ks & 3;            // batch slot this thread finalizes
    const int e2sel = P2;               // which of its 2 elems it finalizes
    const u16* __restrict__ Whh16 = dir ? Whh16b : Whh16f;

    __shared__ unsigned int Wl[256 * 65];        // 66,560 B private blocks
    __shared__ unsigned int Hd[2][4][132];       // fp16-pair h, 4,224 B

    const int wbase = tid * 65;

    // ---- one-time weight stage into thread-private LDS block ----
#pragma unroll
    for (int e2 = 0; e2 < 2; e2++)
#pragma unroll
        for (int q = 0; q < 4; q++) {
            const unsigned int* wp =
                (const unsigned int*)(Whh16 + (size_t)(q * 256 + ebase + e2) * HID);
#pragma unroll
            for (int j = 0; j < 2; j++) {
                *(uint4*)&Wl[wbase + ((e2 * 4 + q) * 2 + j) * 4] =
                    *(const uint4*)(wp + 8 * ks + 4 * j);
            }
        }

    float c = ((t0 == 0) ? c0 : cbuf)
        [((size_t)dir * BATCH + bbase + bloc) * HID + ebase + e2sel];

    const int sb = tid >> 6, k4 = tid & 63;   // staging: batch, f4-slot

    const uint2* __restrict__ G2 = (const uint2*)Gin;   // 4 gates fp16 / unit
    const size_t gbase = (size_t)dir * CT * 16384
                       + (size_t)(bbase + bloc) * 256 + ebase + e2sel;
    uint2 gv = G2[gbase];                     // t_local = 0

    __syncthreads();                          // weights staged

    for (int t = t0; t < t0 + CT; t++) {
        const int wslot = t & 1;

        // prefetch Gin for t+1 (overlaps the poll)
        int tln = t + 1 - t0; if (tln >= CT) tln = CT - 1;
        const uint2 gvn = G2[gbase + (size_t)tln * 16384];

        // ---- stage h(t-1): poll packed tag16|h16 words, write LDS ----
        {
            uint2 hp2;
            if (t == 0) {
                float4 hv = ((const float4*)(h0
                    + ((size_t)dir * BATCH + bbase + sb) * HID))[k4];
                hp2.x = __builtin_bit_cast(unsigned int,
                            (h2){(_Float16)hv.x, (_Float16)hv.y});
                hp2.y = __builtin_bit_cast(unsigned int,
                            (h2){(_Float16)hv.z, (_Float16)hv.w});
            } else {
                const unsigned int* hp =
                    htag + ((((size_t)((t - 1) & 1) * 2 + dir) * BATCH + bbase + sb) * HID
                            + 4 * k4);
                const unsigned int tg = (unsigned int)t;
                uint4 v;
                for (;;) {
                    v = poll_load16(hp);
                    if (((v.x >> 16) == tg) & ((v.y >> 16) == tg) &
                        ((v.z >> 16) == tg) & ((v.w >> 16) == tg))
                        break;
                    __builtin_amdgcn_s_sleep(1);
                }
                hp2.x = (v.x & 0xFFFFu) | (v.y << 16);
                hp2.y = (v.z & 0xFFFFu) | (v.w << 16);
            }
            *(uint2*)&Hd[wslot][sb][2 * k4] = hp2;
        }
        __syncthreads();

        // ---- fp16 dot2 GEMV: 8 rows x 4 batches x 16 k ----
        float a[2][4][4];
#pragma unroll
        for (int e2 = 0; e2 < 2; e2++)
#pragma unroll
            for (int q = 0; q < 4; q++)
#pragma unroll
                for (int b = 0; b < 4; b++) a[e2][q][b] = 0.f;

#pragma unroll
        for (int i2 = 0; i2 < 2; i2++) {
            const int co = 8 * ks + 4 * i2;
            uint4 h4[4];
#pragma unroll
            for (int b = 0; b < 4; b++)
                h4[b] = *(const uint4*)&Hd[wslot][b][co];
#pragma unroll
            for (int e2 = 0; e2 < 2; e2++)
#pragma unroll
                for (int q = 0; q < 4; q++) {
                    const uint4 w4 =
                        *(const uint4*)&Wl[wbase + ((e2 * 4 + q) * 2 + i2) * 4];
#pragma unroll
                    for (int b = 0; b < 4; b++) {
                        a[e2][q][b] = dot2_f16(w4.x, h4[b].x, a[e2][q][b]);
                        a[e2][q][b] = dot2_f16(w4.y, h4[b].y, a[e2][q][b]);
                        a[e2][q][b] = dot2_f16(w4.z, h4[b].z, a[e2][q][b]);
                        a[e2][q][b] = dot2_f16(w4.w, h4[b].w, a[e2][q][b]);
                    }
                }
        }

        // ---- reduce-scatter over lane^{1,2,4,8} ----
        float gfin[4];
#pragma unroll
        for (int q = 0; q < 4; q++) {
            float m[2][2];
#pragma unroll
            for (int e2 = 0; e2 < 2; e2++) {
                float s01 = P0 ? a[e2][q][0] : a[e2][q][1];
                float s23 = P0 ? a[e2][q][2] : a[e2][q][3];
                m[e2][0] = (P0 ? a[e2][q][1] : a[e2][q][0]) + __shfl_xor(s01, 1, 64);
                m[e2][1] = (P0 ? a[e2][q][3] : a[e2][q][2]) + __shfl_xor(s23, 1, 64);
            }
            float gq[2];
#pragma unroll
            for (int e2 = 0; e2 < 2; e2++) {
                float s = P1 ? m[e2][0] : m[e2][1];
                gq[e2] = (P1 ? m[e2][1] : m[e2][0]) + __shfl_xor(s, 2, 64);
            }
            float s = P2 ? gq[0] : gq[1];
            float gk = (P2 ? gq[1] : gq[0]) + __shfl_xor(s, 4, 64);
            gk += __shfl_xor(gk, 8, 64);
            gfin[q] = gk;
        }

        // ---- cell update for (ee = ebase+e2sel, b = bbase+bloc) ----
        const h2 g01 = __builtin_bit_cast(h2, gv.x);
        const h2 g23 = __builtin_bit_cast(h2, gv.y);
        const float x0 = gfin[0] + (float)g01.x;   // i
        const float x1 = gfin[1] + (float)g01.y;   // f
        const float x2 = gfin[2] + (float)g23.x;   // g
        const float x3 = gfin[3] + (float)g23.y;   // o
        c = (1.f / (1.f + expf(-x1))) * c + (1.f / (1.f + expf(-x0))) * tanhf(x2);
        const float h = (1.f / (1.f + expf(-x3))) * tanhf(c);
        gv = gvn;

        if (ks < 8) {
            const int ee = ebase + e2sel;
            const int t_orig = dir ? (LSEQ - 1 - t) : t;
            const unsigned int pkt =
                ((unsigned int)(t + 1) << 16)
                | (unsigned int)__builtin_bit_cast(u16, (_Float16)h);
            __hip_atomic_store(
                &htag[(((size_t)wslot * 2 + dir) * BATCH + bbase + bloc) * HID + ee],
                pkt, __ATOMIC_RELAXED, __HIP_MEMORY_SCOPE_AGENT);
            hs[((size_t)(dir * LSEQ + t_orig) * BATCH + bbase + bloc) * HID + ee] = h;
        }
    }
    if (ks < 8)
        cbuf[((size_t)dir * BATCH + bbase + bloc) * HID + ebase + e2sel] = c;
}

// ---------------- output projection: logits[b][t][11] ----------------
__global__ void __launch_bounds__(256) logits_k(
    const float* __restrict__ hs, const float* __restrict__ Wout,
    const float* __restrict__ bout, float* __restrict__ logits)
{
    const int tid = threadIdx.x;
    const int rt = tid >> 4, tg = tid & 15;
    __shared__ float hrow[16][516];
    __shared__ float Wl[NTAG][516];
    const int rbase = blockIdx.x * 16;

#pragma unroll
    for (int i = 0; i < 8; i++) {
        int u  = tid + i * 256;
        int rr = u >> 7, c4 = u & 127;
        int r_g = rbase + rr;
        int b = r_g >> 9, t = r_g & 511;
        int d = (c4 >= 64) ? 1 : 0, k4 = c4 & 63;
        float4 hv = ((const float4*)hs)[(((size_t)d * LSEQ + t) * BATCH + b) * 64 + k4];
        *(float4*)&hrow[rr][c4 * 4] = hv;
    }
    for (int u = tid; u < NTAG * 128; u += 256) {
        int row = u >> 7, c4 = u & 127;
        float4 wv = ((const float4*)Wout)[(size_t)row * 128 + c4];
        *(float4*)&Wl[row][c4 * 4] = wv;
    }
    __syncthreads();

    if (tg < NTAG) {
        const float4* hp = (const float4*)&hrow[rt][0];
        const float4* wp = (const float4*)&Wl[tg][0];
        float acc = 0.f;
#pragma unroll 4
        for (int k = 0; k < 128; k++) {
            float4 h = hp[k], ww = wp[k];
            acc = fmaf(h.x, ww.x, acc); acc = fmaf(h.y, ww.y, acc);
            acc = fmaf(h.z, ww.z, acc); acc = fmaf(h.w, ww.w, acc);
        }
        int r_g = rbase + rt;
        logits[(size_t)r_g * NTAG + tg] = acc + bout[tg];
    }
}

// ---------------- Viterbi (one wave per batch element) ----------------
__global__ void __launch_bounds__(64) viterbi_k(
    const float* __restrict__ logits, const float* __restrict__ trans,
    float* __restrict__ out)
{
    const int b = blockIdx.x, lane = threadIdx.x;
    __shared__ float lgl[LSEQ * NTAG];
    __shared__ unsigned char bp[LSEQ][16];
    __shared__ float pathf[LSEQ];

    {
        const float4* src = (const float4*)(logits + (size_t)b * LSEQ * NTAG);
        float4* dst = (float4*)lgl;
        for (int u = lane; u < (LSEQ * NTAG) / 4; u += 64) dst[u] = src[u];
    }
    float tcol[NTAG];
    if (lane < NTAG) {
#pragma unroll
        for (int i = 0; i < NTAG; i++) tcol[i] = trans[i * NTAG + lane];
    }
    __syncthreads();

    float v = (lane < NTAG) ? lgl[lane] : -1e30f;
    for (int t = 1; t < LSEQ; t++) {
        float best = -1e30f; int bi = 0;
#pragma unroll
        for (int i = 0; i < NTAG; i++) {
            float vi = __shfl(v, i, 64) + tcol[i];
            if (vi > best) { best = vi; bi = i; }   // strict > == first-max
        }
        if (lane < NTAG) {
            v = lgl[t * NTAG + lane] + best;
            bp[t][lane] = (unsigned char)bi;
        }
    }
    float bestv = -1e30f; int bestj = 0;
#pragma unroll
    for (int j = 0; j < NTAG; j++) {
        float vj = __shfl(v, j, 64);
        if (vj > bestv) { bestv = vj; bestj = j; }
    }
    if (lane == 0) {
        out[b] = bestv;
        int st = bestj;
        pathf[LSEQ - 1] = (float)st;
        for (int t = LSEQ - 1; t >= 1; t--) { st = bp[t][st]; pathf[t - 1] = (float)st; }
    }
    __syncthreads();
    for (int t = lane; t < LSEQ; t += 64)
        out[BATCH + (size_t)b * LSEQ + t] = pathf[t];
}

// ---------------- host ----------------
extern "C" void kernel_launch(void* const* d_in, const int* in_sizes, int n_in,
                              void* d_out, int out_size, void* d_ws, size_t ws_size,
                              hipStream_t stream)
{
    (void)in_sizes; (void)n_in; (void)out_size;
    const int*   sent  = (const int*)  d_in[0];
    const float* emb   = (const float*)d_in[1];
    const float* Wihf  = (const float*)d_in[2];
    const float* Whhf  = (const float*)d_in[3];
    const float* bf    = (const float*)d_in[4];
    const float* Wihb  = (const float*)d_in[5];
    const float* Whhb  = (const float*)d_in[6];
    const float* bb    = (const float*)d_in[7];
    const float* Wout  = (const float*)d_in[8];
    const float* bout  = (const float*)d_in[9];
    const float* trans = (const float*)d_in[10];
    const float* h0    = (const float*)d_in[11];
    const float* c0    = (const float*)d_in[12];
    float* out = (float*)d_out;

    // ws (floats): Gin16[CT*65536] | hs[16777216] | htag[262144] | cbuf[32768]
    //  | logits[360448] | embb[4096000] | w16f[131072] | w16b[131072]
    //  | whh16f[131072] | whh16b[131072]
    const size_t fixed = 16777216ull + 262144ull + 32768ull + 360448ull
                       + 4096000ull + 131072ull + 131072ull
                       + 131072ull + 131072ull;
    int CT = LSEQ;
    while (CT > 8 && ((size_t)CT * 65536ull + fixed) * 4ull > ws_size) CT >>= 1;

    float* ws = (float*)d_ws;
    size_t off = 0;
    u16* Gin = (u16*)(ws + off); off += (size_t)CT * 65536ull;
    float* hs   = ws + off; off += 16777216ull;
    unsigned int* htag = (unsigned int*)(ws + off); off += 262144ull;
    float* cbuf = ws + off; off += 32768ull;
    float* lgts = ws + off; off += 360448ull;
    u16* embb = (u16*)(ws + off); off += 4096000ull;
    u16* w16f = (u16*)(ws + off); off += 131072ull;
    u16* w16b = (u16*)(ws + off); off += 131072ull;
    u16* whh16f = (u16*)(ws + off); off += 131072ull;
    u16* whh16b = (u16*)(ws + off); off += 131072ull;

    hipLaunchKernelGGL(cvt_bf16, dim3(2048), dim3(256), 0, stream,
                       emb, embb, (32000 * 256) / 4);
    hipLaunchKernelGGL(cvt_bf16, dim3(256), dim3(256), 0, stream,
                       Wihf, w16f, (1024 * 256) / 4);
    hipLaunchKernelGGL(cvt_bf16, dim3(256), dim3(256), 0, stream,
                       Wihb, w16b, (1024 * 256) / 4);
    hipLaunchKernelGGL(cvt_f16, dim3(256), dim3(256), 0, stream,
                       Whhf, whh16f, (1024 * 256) / 4);
    hipLaunchKernelGGL(cvt_f16, dim3(256), dim3(256), 0, stream,
                       Whhb, whh16b, (1024 * 256) / 4);

    const int nch = LSEQ / CT;
    for (int c = 0; c < nch; c++) {
        int t0 = c * CT;
        hipLaunchKernelGGL(gemm_in, dim3(CT / 2, 8, 2), dim3(256), 0, stream,
                           sent, embb, w16f, w16b, bf, bb, Gin, t0, CT);
        hipLaunchKernelGGL(lstm_rec, dim3(256), dim3(256), 0, stream,
                           Gin, whh16f, whh16b, h0, c0, hs, htag, cbuf, t0, CT);
    }
    hipLaunchKernelGGL(logits_k, dim3((BATCH * LSEQ) / 16), dim3(256), 0, stream,
                       hs, Wout, bout, lgts);
    hipLaunchKernelGGL(viterbi_k, dim3(BATCH), dim3(64), 0, stream,
                       lgts, trans, out);
}

// Round 10
// 1524.182 us; speedup vs baseline: 2.9207x; 1.0747x over previous
//
#include <hip/hip_runtime.h>
#include <cstdint>
#include <cstddef>
#include <cstring>

#define LSEQ 512
#define BATCH 64
#define DIM 256
#define HID 256
#define NTAG 11

typedef float vf4 __attribute__((ext_vector_type(4)));
typedef __bf16 bf16x8 __attribute__((ext_vector_type(8)));
typedef float f32x4 __attribute__((ext_vector_type(4)));
typedef _Float16 h2 __attribute__((ext_vector_type(2)));
typedef unsigned short u16;

static __device__ __forceinline__ float dot2_f16(unsigned int w, unsigned int h, float acc)
{
#if __has_builtin(__builtin_amdgcn_fdot2)
    return __builtin_amdgcn_fdot2(__builtin_bit_cast(h2, w),
                                  __builtin_bit_cast(h2, h), acc, false);
#else
    h2 a = __builtin_bit_cast(h2, w), b = __builtin_bit_cast(h2, h);
    acc = fmaf((float)a.x, (float)b.x, acc);
    return fmaf((float)a.y, (float)b.y, acc);
#endif
}

// Fast transcendentals on the serial critical path: v_exp_f32 + v_rcp_f32
// (~6 cyc each) replace 20-40-instr library expf/tanhf sequences.  Error
// ~1e-6 relative — 3 orders below the fp16 h-quantization already in use.
// Saturation: exp2(+inf)->inf => sig->0/1, tanh->+-1; no NaN paths.
static __device__ __forceinline__ float fast_sig(float x)
{
#if __has_builtin(__builtin_amdgcn_exp2f) && __has_builtin(__builtin_amdgcn_rcpf)
    return __builtin_amdgcn_rcpf(1.f + __builtin_amdgcn_exp2f(x * -1.442695041f));
#else
    return 1.f / (1.f + expf(-x));
#endif
}
static __device__ __forceinline__ float fast_tanh(float x)
{
#if __has_builtin(__builtin_amdgcn_exp2f) && __has_builtin(__builtin_amdgcn_rcpf)
    // tanh(x) = 1 - 2/(e^{2x}+1)
    return 1.f - 2.f * __builtin_amdgcn_rcpf(__builtin_amdgcn_exp2f(x * 2.885390082f) + 1.f);
#else
    return tanhf(x);
#endif
}

// 16B coherent poll load: bypasses L1/L2 (sc0 sc1) so remote XCD publishes
// are visible; single request replaces 4x8B atomic loads.
static __device__ __forceinline__ uint4 poll_load16(const unsigned int* p)
{
    uint4 v;
    asm volatile("global_load_dwordx4 %0, %1, off sc0 sc1\n"
                 "s_waitcnt vmcnt(0)"
                 : "=&v"(v) : "v"(p) : "memory");
    return v;
}

// ---------------- fp32 -> bf16 (RNE) convert ----------------
__global__ void __launch_bounds__(256) cvt_bf16(
    const float* __restrict__ src, u16* __restrict__ dst, int n4)
{
    int i = blockIdx.x * blockDim.x + threadIdx.x;
    const int stride = gridDim.x * blockDim.x;
    for (; i < n4; i += stride) {
        float4 f = ((const float4*)src)[i];
        ushort4 r;
        unsigned int u;
        u = __float_as_uint(f.x); u += 0x7FFFu + ((u >> 16) & 1u); r.x = (u16)(u >> 16);
        u = __float_as_uint(f.y); u += 0x7FFFu + ((u >> 16) & 1u); r.y = (u16)(u >> 16);
        u = __float_as_uint(f.z); u += 0x7FFFu + ((u >> 16) & 1u); r.z = (u16)(u >> 16);
        u = __float_as_uint(f.w); u += 0x7FFFu + ((u >> 16) & 1u); r.w = (u16)(u >> 16);
        ((ushort4*)dst)[i] = r;
    }
}

// ---------------- fp32 -> fp16 (RNE) convert ----------------
__global__ void __launch_bounds__(256) cvt_f16(
    const float* __restrict__ src, u16* __restrict__ dst, int n4)
{
    int i = blockIdx.x * blockDim.x + threadIdx.x;
    const int stride = gridDim.x * blockDim.x;
    for (; i < n4; i += stride) {
        float4 f = ((const float4*)src)[i];
        ushort4 r;
        r.x = __builtin_bit_cast(u16, (_Float16)f.x);
        r.y = __builtin_bit_cast(u16, (_Float16)f.y);
        r.z = __builtin_bit_cast(u16, (_Float16)f.z);
        r.w = __builtin_bit_cast(u16, (_Float16)f.w);
        ((ushort4*)dst)[i] = r;
    }
}

// ---------------- input GEMM via bf16 MFMA (+gather, +bias) ----------------
// Epilogue writes gate-contiguous fp16 Gin:
//   u16 index (((dir*CT + tl)*64 + b)*256 + e)*4 + q    (n = q*256 + e)
__global__ void __launch_bounds__(256) gemm_in(
    const int* __restrict__ sent, const u16* __restrict__ embb,
    const u16* __restrict__ w16f, const u16* __restrict__ w16b,
    const float* __restrict__ bf_, const float* __restrict__ bb_,
    u16* __restrict__ Gin, int t0, int CT)
{
    const int mtile = blockIdx.x, ntile = blockIdx.y, dir = blockIdx.z;
    const u16* __restrict__ W16 = dir ? w16b : w16f;
    const float* __restrict__ bias = dir ? bb_ : bf_;
    const int tid = threadIdx.x;
    const int wave = tid >> 6, lane = tid & 63;
    const int wm = wave & 1, wn = wave >> 1;

    __shared__ u16 Asm[128][40];   // [m][k] pitch 40 (2-way max on frag reads)
    __shared__ u16 Bsm[128][40];   // [n][k]

    const int row = tid >> 1, half = tid & 1;
    const u16* ap;
    {
        int m_g = mtile * 128 + row;
        int tl = m_g >> 6, b = m_g & 63;
        int tg = t0 + tl;
        int tt = dir ? (LSEQ - 1 - tg) : tg;
        ap = embb + (size_t)sent[b * LSEQ + tt] * DIM;
    }
    const u16* bp = W16 + (size_t)(ntile * 128 + row) * DIM;

    f32x4 acc[4][4];
#pragma unroll
    for (int i = 0; i < 4; i++)
#pragma unroll
        for (int j = 0; j < 4; j++) acc[i][j] = (f32x4){0.f, 0.f, 0.f, 0.f};

    const int col = lane & 15, quad = lane >> 4;

    for (int ki = 0; ki < 8; ki++) {
        const int k0 = ki * 32;
        __syncthreads();
        {
            uint4 a0 = *(const uint4*)(ap + k0 + half * 16);
            uint4 a1 = *(const uint4*)(ap + k0 + half * 16 + 8);
            uint4 b0 = *(const uint4*)(bp + k0 + half * 16);
            uint4 b1 = *(const uint4*)(bp + k0 + half * 16 + 8);
            *(uint4*)&Asm[row][half * 16 + 0] = a0;
            *(uint4*)&Asm[row][half * 16 + 8] = a1;
            *(uint4*)&Bsm[row][half * 16 + 0] = b0;
            *(uint4*)&Bsm[row][half * 16 + 8] = b1;
        }
        __syncthreads();

        bf16x8 af[4], bg[4];
#pragma unroll
        for (int i = 0; i < 4; i++) {
            af[i] = *(const bf16x8*)&Asm[wm * 64 + i * 16 + col][quad * 8];
            bg[i] = *(const bf16x8*)&Bsm[wn * 64 + i * 16 + col][quad * 8];
        }
#pragma unroll
        for (int mt = 0; mt < 4; mt++)
#pragma unroll
            for (int nt = 0; nt < 4; nt++)
                acc[mt][nt] = __builtin_amdgcn_mfma_f32_16x16x32_bf16(
                    af[mt], bg[nt], acc[mt][nt], 0, 0, 0);
    }

#pragma unroll
    for (int nt = 0; nt < 4; nt++) {
        const int n_g = ntile * 128 + wn * 64 + nt * 16 + col;
        const float bv = bias[n_g];
        const int q = n_g >> 8, e = n_g & 255;
#pragma unroll
        for (int mt = 0; mt < 4; mt++)
#pragma unroll
            for (int r = 0; r < 4; r++) {
                const int m_g = mtile * 128 + wm * 64 + mt * 16 + quad * 4 + r;
                const int tl = m_g >> 6, b = m_g & 63;
                Gin[(((size_t)(dir * CT + tl) * 64 + b) * 256 + e) * 4 + q]
                    = __builtin_bit_cast(u16, (_Float16)(acc[mt][nt][r] + bv));
            }
    }
}

// ---------------- persistent bidirectional LSTM recurrence ------
// r8 (congestion cuts) landed: 2.55us/step (was 3.30).  Remaining step =
// exchange RT (~800-1000cy, structural: weights don't fit one CU => >=4-way
// partition => exchange; M=8 = scanned minimum) + VALU ~2200cy.  The only
// un-hidden VALU is the cell update: 6 library transcendentals (4 sigmoid
// + 2 tanh = ~250 instrs) sit AFTER the reduce and BEFORE the publish on
// the serial chain.  This round: hardware v_exp_f32/v_rcp_f32 versions
// (fast_sig/fast_tanh) — ~400-500 cyc off every step's tail.
// (r9 bench was an infra container failure — resubmitting unchanged.)
// Structure identical to r8: 256 WGs = 32 groups x 8 members; 32-bit
// packed exchange word (t+1)<<16 | fp16(h); poll = one dwordx4 sc0 sc1;
// fp16 Gin, CT=512 single dispatch; weights in thread-private LDS blocks
// (pitch 65); reduce-scatter over lane^{1,2,4,8}.
__global__ void __launch_bounds__(256, 1) lstm_rec(
    const u16* __restrict__ Gin,
    const u16* __restrict__ Whh16f, const u16* __restrict__ Whh16b,
    const float* __restrict__ h0, const float* __restrict__ c0,
    float* __restrict__ hs, unsigned int* __restrict__ htag,
    float* __restrict__ cbuf, int t0, int CT)
{
    const int wg = blockIdx.x;
    const int w = wg >> 5, g = wg & 31;
    const int dir   = g >> 4;
    const int bbase = (g & 15) << 2;
    const int tid = threadIdx.x;
    const int ks = tid & 15;            // k-slice index (16 halves = 8 dwords)
    const int ep = tid >> 4;            // ee-pair index 0..15
    const int ebase = w * 32 + ep * 2;  // first of the 2 hidden elems
    const int P0 = ks & 1, P1 = (ks >> 1) & 1, P2 = (ks >> 2) & 1;
    const int bloc = ks & 3;            // batch slot this thread finalizes
    const int e2sel = P2;               // which of its 2 elems it finalizes
    const u16* __restrict__ Whh16 = dir ? Whh16b : Whh16f;

    __shared__ unsigned int Wl[256 * 65];        // 66,560 B private blocks
    __shared__ unsigned int Hd[2][4][132];       // fp16-pair h, 4,224 B

    const int wbase = tid * 65;

    // ---- one-time weight stage into thread-private LDS block ----
#pragma unroll
    for (int e2 = 0; e2 < 2; e2++)
#pragma unroll
        for (int q = 0; q < 4; q++) {
            const unsigned int* wp =
                (const unsigned int*)(Whh16 + (size_t)(q * 256 + ebase + e2) * HID);
#pragma unroll
            for (int j = 0; j < 2; j++) {
                *(uint4*)&Wl[wbase + ((e2 * 4 + q) * 2 + j) * 4] =
                    *(const uint4*)(wp + 8 * ks + 4 * j);
            }
        }

    float c = ((t0 == 0) ? c0 : cbuf)
        [((size_t)dir * BATCH + bbase + bloc) * HID + ebase + e2sel];

    const int sb = tid >> 6, k4 = tid & 63;   // staging: batch, f4-slot

    const uint2* __restrict__ G2 = (const uint2*)Gin;   // 4 gates fp16 / unit
    const size_t gbase = (size_t)dir * CT * 16384
                       + (size_t)(bbase + bloc) * 256 + ebase + e2sel;
    uint2 gv = G2[gbase];                     // t_local = 0

    __syncthreads();                          // weights staged

    for (int t = t0; t < t0 + CT; t++) {
        const int wslot = t & 1;

        // prefetch Gin for t+1 (overlaps the poll)
        int tln = t + 1 - t0; if (tln >= CT) tln = CT - 1;
        const uint2 gvn = G2[gbase + (size_t)tln * 16384];

        // ---- stage h(t-1): poll packed tag16|h16 words, write LDS ----
        {
            uint2 hp2;
            if (t == 0) {
                float4 hv = ((const float4*)(h0
                    + ((size_t)dir * BATCH + bbase + sb) * HID))[k4];
                hp2.x = __builtin_bit_cast(unsigned int,
                            (h2){(_Float16)hv.x, (_Float16)hv.y});
                hp2.y = __builtin_bit_cast(unsigned int,
                            (h2){(_Float16)hv.z, (_Float16)hv.w});
            } else {
                const unsigned int* hp =
                    htag + ((((size_t)((t - 1) & 1) * 2 + dir) * BATCH + bbase + sb) * HID
                            + 4 * k4);
                const unsigned int tg = (unsigned int)t;
                uint4 v;
                for (;;) {
                    v = poll_load16(hp);
                    if (((v.x >> 16) == tg) & ((v.y >> 16) == tg) &
                        ((v.z >> 16) == tg) & ((v.w >> 16) == tg))
                        break;
                    __builtin_amdgcn_s_sleep(1);
                }
                hp2.x = (v.x & 0xFFFFu) | (v.y << 16);
                hp2.y = (v.z & 0xFFFFu) | (v.w << 16);
            }
            *(uint2*)&Hd[wslot][sb][2 * k4] = hp2;
        }
        __syncthreads();

        // ---- fp16 dot2 GEMV: 8 rows x 4 batches x 16 k ----
        float a[2][4][4];
#pragma unroll
        for (int e2 = 0; e2 < 2; e2++)
#pragma unroll
            for (int q = 0; q < 4; q++)
#pragma unroll
                for (int b = 0; b < 4; b++) a[e2][q][b] = 0.f;

#pragma unroll
        for (int i2 = 0; i2 < 2; i2++) {
            const int co = 8 * ks + 4 * i2;
            uint4 h4[4];
#pragma unroll
            for (int b = 0; b < 4; b++)
                h4[b] = *(const uint4*)&Hd[wslot][b][co];
#pragma unroll
            for (int e2 = 0; e2 < 2; e2++)
#pragma unroll
                for (int q = 0; q < 4; q++) {
                    const uint4 w4 =
                        *(const uint4*)&Wl[wbase + ((e2 * 4 + q) * 2 + i2) * 4];
#pragma unroll
                    for (int b = 0; b < 4; b++) {
                        a[e2][q][b] = dot2_f16(w4.x, h4[b].x, a[e2][q][b]);
                        a[e2][q][b] = dot2_f16(w4.y, h4[b].y, a[e2][q][b]);
                        a[e2][q][b] = dot2_f16(w4.z, h4[b].z, a[e2][q][b]);
                        a[e2][q][b] = dot2_f16(w4.w, h4[b].w, a[e2][q][b]);
                    }
                }
        }

        // ---- reduce-scatter over lane^{1,2,4,8} ----
        float gfin[4];
#pragma unroll
        for (int q = 0; q < 4; q++) {
            float m[2][2];
#pragma unroll
            for (int e2 = 0; e2 < 2; e2++) {
                float s01 = P0 ? a[e2][q][0] : a[e2][q][1];
                float s23 = P0 ? a[e2][q][2] : a[e2][q][3];
                m[e2][0] = (P0 ? a[e2][q][1] : a[e2][q][0]) + __shfl_xor(s01, 1, 64);
                m[e2][1] = (P0 ? a[e2][q][3] : a[e2][q][2]) + __shfl_xor(s23, 1, 64);
            }
            float gq[2];
#pragma unroll
            for (int e2 = 0; e2 < 2; e2++) {
                float s = P1 ? m[e2][0] : m[e2][1];
                gq[e2] = (P1 ? m[e2][1] : m[e2][0]) + __shfl_xor(s, 2, 64);
            }
            float s = P2 ? gq[0] : gq[1];
            float gk = (P2 ? gq[1] : gq[0]) + __shfl_xor(s, 4, 64);
            gk += __shfl_xor(gk, 8, 64);
            gfin[q] = gk;
        }

        // ---- cell update for (ee = ebase+e2sel, b = bbase+bloc) ----
        const h2 g01 = __builtin_bit_cast(h2, gv.x);
        const h2 g23 = __builtin_bit_cast(h2, gv.y);
        const float x0 = gfin[0] + (float)g01.x;   // i
        const float x1 = gfin[1] + (float)g01.y;   // f
        const float x2 = gfin[2] + (float)g23.x;   // g
        const float x3 = gfin[3] + (float)g23.y;   // o
        c = fast_sig(x1) * c + fast_sig(x0) * fast_tanh(x2);
        const float h = fast_sig(x3) * fast_tanh(c);
        gv = gvn;

        if (ks < 8) {
            const int ee = ebase + e2sel;
            const int t_orig = dir ? (LSEQ - 1 - t) : t;
            const unsigned int pkt =
                ((unsigned int)(t + 1) << 16)
                | (unsigned int)__builtin_bit_cast(u16, (_Float16)h);
            __hip_atomic_store(
                &htag[(((size_t)wslot * 2 + dir) * BATCH + bbase + bloc) * HID + ee],
                pkt, __ATOMIC_RELAXED, __HIP_MEMORY_SCOPE_AGENT);
            hs[((size_t)(dir * LSEQ + t_orig) * BATCH + bbase + bloc) * HID + ee] = h;
        }
    }
    if (ks < 8)
        cbuf[((size_t)dir * BATCH + bbase + bloc) * HID + ebase + e2sel] = c;
}

// ---------------- output projection: logits[b][t][11] ----------------
__global__ void __launch_bounds__(256) logits_k(
    const float* __restrict__ hs, const float* __restrict__ Wout,
    const float* __restrict__ bout, float* __restrict__ logits)
{
    const int tid = threadIdx.x;
    const int rt = tid >> 4, tg = tid & 15;
    __shared__ float hrow[16][516];
    __shared__ float Wl[NTAG][516];
    const int rbase = blockIdx.x * 16;

#pragma unroll
    for (int i = 0; i < 8; i++) {
        int u  = tid + i * 256;
        int rr = u >> 7, c4 = u & 127;
        int r_g = rbase + rr;
        int b = r_g >> 9, t = r_g & 511;
        int d = (c4 >= 64) ? 1 : 0, k4 = c4 & 63;
        float4 hv = ((const float4*)hs)[(((size_t)d * LSEQ + t) * BATCH + b) * 64 + k4];
        *(float4*)&hrow[rr][c4 * 4] = hv;
    }
    for (int u = tid; u < NTAG * 128; u += 256) {
        int row = u >> 7, c4 = u & 127;
        float4 wv = ((const float4*)Wout)[(size_t)row * 128 + c4];
        *(float4*)&Wl[row][c4 * 4] = wv;
    }
    __syncthreads();

    if (tg < NTAG) {
        const float4* hp = (const float4*)&hrow[rt][0];
        const float4* wp = (const float4*)&Wl[tg][0];
        float acc = 0.f;
#pragma unroll 4
        for (int k = 0; k < 128; k++) {
            float4 h = hp[k], ww = wp[k];
            acc = fmaf(h.x, ww.x, acc); acc = fmaf(h.y, ww.y, acc);
            acc = fmaf(h.z, ww.z, acc); acc = fmaf(h.w, ww.w, acc);
        }
        int r_g = rbase + rt;
        logits[(size_t)r_g * NTAG + tg] = acc + bout[tg];
    }
}

// ---------------- Viterbi (one wave per batch element) ----------------
__global__ void __launch_bounds__(64) viterbi_k(
    const float* __restrict__ logits, const float* __restrict__ trans,
    float* __restrict__ out)
{
    const int b = blockIdx.x, lane = threadIdx.x;
    __shared__ float lgl[LSEQ * NTAG];
    __shared__ unsigned char bp[LSEQ][16];
    __shared__ float pathf[LSEQ];

    {
        const float4* src = (const float4*)(logits + (size_t)b * LSEQ * NTAG);
        float4* dst = (float4*)lgl;
        for (int u = lane; u < (LSEQ * NTAG) / 4; u += 64) dst[u] = src[u];
    }
    float tcol[NTAG];
    if (lane < NTAG) {
#pragma unroll
        for (int i = 0; i < NTAG; i++) tcol[i] = trans[i * NTAG + lane];
    }
    __syncthreads();

    float v = (lane < NTAG) ? lgl[lane] : -1e30f;
    for (int t = 1; t < LSEQ; t++) {
        float best = -1e30f; int bi = 0;
#pragma unroll
        for (int i = 0; i < NTAG; i++) {
            float vi = __shfl(v, i, 64) + tcol[i];
            if (vi > best) { best = vi; bi = i; }   // strict > == first-max
        }
        if (lane < NTAG) {
            v = lgl[t * NTAG + lane] + best;
            bp[t][lane] = (unsigned char)bi;
        }
    }
    float bestv = -1e30f; int bestj = 0;
#pragma unroll
    for (int j = 0; j < NTAG; j++) {
        float vj = __shfl(v, j, 64);
        if (vj > bestv) { bestv = vj; bestj = j; }
    }
    if (lane == 0) {
        out[b] = bestv;
        int st = bestj;
        pathf[LSEQ - 1] = (float)st;
        for (int t = LSEQ - 1; t >= 1; t--) { st = bp[t][st]; pathf[t - 1] = (float)st; }
    }
    __syncthreads();
    for (int t = lane; t < LSEQ; t += 64)
        out[BATCH + (size_t)b * LSEQ + t] = pathf[t];
}

// ---------------- host ----------------
extern "C" void kernel_launch(void* const* d_in, const int* in_sizes, int n_in,
                              void* d_out, int out_size, void* d_ws, size_t ws_size,
                              hipStream_t stream)
{
    (void)in_sizes; (void)n_in; (void)out_size;
    const int*   sent  = (const int*)  d_in[0];
    const float* emb   = (const float*)d_in[1];
    const float* Wihf  = (const float*)d_in[2];
    const float* Whhf  = (const float*)d_in[3];
    const float* bf    = (const float*)d_in[4];
    const float* Wihb  = (const float*)d_in[5];
    const float* Whhb  = (const float*)d_in[6];
    const float* bb    = (const float*)d_in[7];
    const float* Wout  = (const float*)d_in[8];
    const float* bout  = (const float*)d_in[9];
    const float* trans = (const float*)d_in[10];
    const float* h0    = (const float*)d_in[11];
    const float* c0    = (const float*)d_in[12];
    float* out = (float*)d_out;

    // ws (floats): Gin16[CT*65536] | hs[16777216] | htag[262144] | cbuf[32768]
    //  | logits[360448] | embb[4096000] | w16f[131072] | w16b[131072]
    //  | whh16f[131072] | whh16b[131072]
    const size_t fixed = 16777216ull + 262144ull + 32768ull + 360448ull
                       + 4096000ull + 131072ull + 131072ull
                       + 131072ull + 131072ull;
    int CT = LSEQ;
    while (CT > 8 && ((size_t)CT * 65536ull + fixed) * 4ull > ws_size) CT >>= 1;

    float* ws = (float*)d_ws;
    size_t off = 0;
    u16* Gin = (u16*)(ws + off); off += (size_t)CT * 65536ull;
    float* hs   = ws + off; off += 16777216ull;
    unsigned int* htag = (unsigned int*)(ws + off); off += 262144ull;
    float* cbuf = ws + off; off += 32768ull;
    float* lgts = ws + off; off += 360448ull;
    u16* embb = (u16*)(ws + off); off += 4096000ull;
    u16* w16f = (u16*)(ws + off); off += 131072ull;
    u16* w16b = (u16*)(ws + off); off += 131072ull;
    u16* whh16f = (u16*)(ws + off); off += 131072ull;
    u16* whh16b = (u16*)(ws + off); off += 131072ull;

    hipLaunchKernelGGL(cvt_bf16, dim3(2048), dim3(256), 0, stream,
                       emb, embb, (32000 * 256) / 4);
    hipLaunchKernelGGL(cvt_bf16, dim3(256), dim3(256), 0, stream,
                       Wihf, w16f, (1024 * 256) / 4);
    hipLaunchKernelGGL(cvt_bf16, dim3(256), dim3(256), 0, stream,
                       Wihb, w16b, (1024 * 256) / 4);
    hipLaunchKernelGGL(cvt_f16, dim3(256), dim3(256), 0, stream,
                       Whhf, whh16f, (1024 * 256) / 4);
    hipLaunchKernelGGL(cvt_f16, dim3(256), dim3(256), 0, stream,
                       Whhb, whh16b, (1024 * 256) / 4);

    const int nch = LSEQ / CT;
    for (int c = 0; c < nch; c++) {
        int t0 = c * CT;
        hipLaunchKernelGGL(gemm_in, dim3(CT / 2, 8, 2), dim3(256), 0, stream,
                           sent, embb, w16f, w16b, bf, bb, Gin, t0, CT);
        hipLaunchKernelGGL(lstm_rec, dim3(256), dim3(256), 0, stream,
                           Gin, whh16f, whh16b, h0, c0, hs, htag, cbuf, t0, CT);
    }
    hipLaunchKernelGGL(logits_k, dim3((BATCH * LSEQ) / 16), dim3(256), 0, stream,
                       hs, Wout, bout, lgts);
    hipLaunchKernelGGL(viterbi_k, dim3(BATCH), dim3(64), 0, stream,
                       lgts, trans, out);
}